// Round 6
// baseline (348.160 us; speedup 1.0000x reference)
//
#include <hip/hip_runtime.h>

#define NT 128
#define SS 512
#define PW 132                          // padded per-wave column stride (floats)

typedef float f32x2 __attribute__((ext_vector_type(2)));

__device__ __forceinline__ float rdlanef(float v, int lane) {
    return __int_as_float(__builtin_amdgcn_readlane(__float_as_int(v), lane));
}
__device__ __forceinline__ int fexp_of(float x) {
    return (int)((__float_as_uint(x) >> 23) & 0xFFu) - 127;
}
// barrier draining only LDS ops — global prefetches stay in flight
__device__ __forceinline__ void lds_barrier() {
    asm volatile("s_waitcnt lgkmcnt(0)\n\ts_barrier" ::: "memory");
}

__global__ void zero_out_kernel(float* out) { out[0] = 0.0f; }

// R0 structure (4 waves x 32 rows, readlane + pk_fma) but TWO sequences per
// block: independent streams fill the ~50% dependency bubbles, and the exp(T)
// table is shared. K-rescale anchored on state 0 (no shuffle-reduce chain).
__global__ __launch_bounds__(256, 1) void crf_fwd_kernel(
    const float* __restrict__ emissions,        // [B, S, NT] f32
    const int* __restrict__ tags,               // [B, S]
    const unsigned char* __restrict__ mask,     // [B, S]
    const float* __restrict__ trans,            // [NT, NT] f32
    float* __restrict__ out)                    // [1] f32
{
    const int tid = threadIdx.x;                // 0..255
    const int l   = tid & 63;
    const int w   = tid >> 6;                   // wave 0..3: rows/states 32w..32w+31
    const int st  = (w << 5) + (l & 31);        // owned state (dup on lane halves)
    const int bA  = blockIdx.x * 2;             // two batches per block
    const int bB  = bA + 1;

    __shared__ float pbuf[2][2][4 * PW];        // [parity][seq][wave*PW + col]
    __shared__ int   kslotA, kslotB;
    __shared__ float redf[2][4];
    __shared__ float redg[2][4];

    const float*         emA  = emissions + (size_t)bA * SS * NT;
    const float*         emBs = emissions + (size_t)bB * SS * NT;
    const int*           tgA  = tags + bA * SS;
    const int*           tgB  = tags + bB * SS;
    const unsigned char* mkA  = mask + bA * SS;
    const unsigned char* mkB  = mask + bB * SS;

    // ---- gold scores fully hoisted off the recursion ----
    float goldA = 0.0f, goldB = 0.0f;
    for (int t = tid; t < SS; t += 256) {
        int ta = tgA[t];
        float ma = mkA[t] ? 1.0f : 0.0f;
        float aa = emA[(size_t)t * NT + ta];
        if (t > 0) aa += trans[tgA[t - 1] * NT + ta];
        goldA += aa * ma;
        int tb = tgB[t];
        float mb = mkB[t] ? 1.0f : 0.0f;
        float ab = emBs[(size_t)t * NT + tb];
        if (t > 0) ab += trans[tgB[t - 1] * NT + tb];
        goldB += ab * mb;
    }

    // ---- expT: own 32 rows, cols {l, l+64} packed — SHARED by both seqs ----
    f32x2 eTr[32];
    #pragma unroll
    for (int r = 0; r < 32; r++) {
        const float* row = trans + (size_t)((w << 5) + r) * NT;
        f32x2 v; v.x = __expf(row[l]); v.y = __expf(row[l + 64]);
        eTr[r] = v;
    }

    // ---- init: pX = exp(a0 - M0X) per seq ----
    float a0A = emA[st], a0B = emBs[st];
    {
        float vA = a0A, vB = a0B;
        #pragma unroll
        for (int o = 16; o > 0; o >>= 1) {
            vA = fmaxf(vA, __shfl_xor(vA, o));
            vB = fmaxf(vB, __shfl_xor(vB, o));
        }
        if (l == 0) { redf[0][w] = vA; redf[1][w] = vB; }
    }
    __syncthreads();
    const float M0A = fmaxf(fmaxf(redf[0][0], redf[0][1]), fmaxf(redf[0][2], redf[0][3]));
    const float M0B = fmaxf(fmaxf(redf[1][0], redf[1][1]), fmaxf(redf[1][2], redf[1][3]));

    float pA = __expf(a0A - M0A);
    float pB = __expf(a0B - M0B);
    float SA = 0.0f, SB = 0.0f;
    int KA = 0, KB = 0, kvA = 0, kvB = 0;

    // ---- emission pipelines (per seq): loads 4 deep, exp 2 steps off-chain ----
    float exA_o = __expf(emA[(size_t)1 * NT + st]);
    float exA_e = __expf(emA[(size_t)2 * NT + st]);
    float pdA_o = emA[(size_t)3 * NT + st];
    float pdA_e = emA[(size_t)4 * NT + st];
    float exB_o = __expf(emBs[(size_t)1 * NT + st]);
    float exB_e = __expf(emBs[(size_t)2 * NT + st]);
    float pdB_o = emBs[(size_t)3 * NT + st];
    float pdB_e = emBs[(size_t)4 * NT + st];

    // matvec over own 32 rows (R0's measured-best form)
    auto matvec = [&](float pp) -> f32x2 {
        f32x2 A0 = {0.f,0.f}, A1 = {0.f,0.f}, A2 = {0.f,0.f}, A3 = {0.f,0.f};
        #pragma unroll
        for (int r = 0; r < 32; r += 4) {
            float q0 = rdlanef(pp, r + 0);
            float q1 = rdlanef(pp, r + 1);
            float q2 = rdlanef(pp, r + 2);
            float q3 = rdlanef(pp, r + 3);
            f32x2 b0 = {q0, q0}, b1 = {q1, q1}, b2 = {q2, q2}, b3 = {q3, q3};
            A0 = __builtin_elementwise_fma(b0, eTr[r + 0], A0);
            A1 = __builtin_elementwise_fma(b1, eTr[r + 1], A1);
            A2 = __builtin_elementwise_fma(b2, eTr[r + 2], A2);
            A3 = __builtin_elementwise_fma(b3, eTr[r + 3], A3);
        }
        return (A0 + A1) + (A2 + A3);           // {partial col l, partial col l+64}
    };
    auto comb = [&](int q, int s) -> float {
        return (pbuf[q][s][0 * PW + st] + pbuf[q][s][1 * PW + st]) +
               (pbuf[q][s][2 * PW + st] + pbuf[q][s][3 * PW + st]);
    };
    auto wr = [&](int q, int s, f32x2 v) {
        pbuf[q][s][w * PW + l]      = v.x;
        pbuf[q][s][w * PW + l + 64] = v.y;
    };
    auto rot = [&](const float* em, int t, float& pd, float& ex) {
        float nr = pd;
        int tn = t + 4; if (tn > SS - 1) tn = SS - 1;
        pd = em[(size_t)tn * NT + st];
        ex = __expf(nr);
    };

    // ---- forward recursion: groups of 4 steps; rescale at sub-step 0 ----
    #pragma unroll 1
    for (int t = 1; t < SS; t += 4) {
        {   // sub 0 (parity 1): apply K, propose next kv (state-0 anchor)
            f32x2 sA = matvec(pA); f32x2 sB = matvec(pB);
            wr(1, 0, sA); wr(1, 1, sB);
            lds_barrier();
            float cA = comb(1, 0), cB = comb(1, 1);
            pA = ldexpf(cA * exA_o, -KA); SA += (float)KA;
            pB = ldexpf(cB * exB_o, -KB); SB += (float)KB;
            kvA = fexp_of(pA);                  // only wave0-lane0's value is used
            kvB = fexp_of(pB);
            rot(emA, t, pdA_o, exA_o);
            rot(emBs, t, pdB_o, exB_o);
        }
        if (t + 1 < SS) {   // sub 1 (parity 0): K anchors ride the barrier
            f32x2 sA = matvec(pA); f32x2 sB = matvec(pB);
            wr(0, 0, sA); wr(0, 1, sB);
            if (w == 0 && l == 0) { kslotA = kvA; kslotB = kvB; }
            lds_barrier();
            pA = comb(0, 0) * exA_e;
            pB = comb(0, 1) * exB_e;
            KA = kslotA; KB = kslotB;           // uniform reads, off-chain
            rot(emA, t + 1, pdA_e, exA_e);
            rot(emBs, t + 1, pdB_e, exB_e);
        }
        if (t + 2 < SS) {   // sub 2 (parity 1)
            f32x2 sA = matvec(pA); f32x2 sB = matvec(pB);
            wr(1, 0, sA); wr(1, 1, sB);
            lds_barrier();
            pA = comb(1, 0) * exA_o;
            pB = comb(1, 1) * exB_o;
            rot(emA, t + 2, pdA_o, exA_o);
            rot(emBs, t + 2, pdB_o, exB_o);
        }
        if (t + 3 < SS) {   // sub 3 (parity 0)
            f32x2 sA = matvec(pA); f32x2 sB = matvec(pB);
            wr(0, 0, sA); wr(0, 1, sB);
            lds_barrier();
            pA = comb(0, 0) * exA_e;
            pB = comb(0, 1) * exB_e;
            rot(emA, t + 3, pdA_e, exA_e);
            rot(emBs, t + 3, pdB_e, exB_e);
        }
    }

    // ---- epilogue: partition = M0 + S*ln2 + log Σ p̂ ; reduce golds ----
    {
        float swA = (l < 32) ? pA : 0.0f;       // states duplicated on lane halves
        float swB = (l < 32) ? pB : 0.0f;
        float gA = goldA, gB = goldB;
        #pragma unroll
        for (int o = 32; o > 0; o >>= 1) {
            swA += __shfl_xor(swA, o);
            swB += __shfl_xor(swB, o);
            gA  += __shfl_xor(gA, o);
            gB  += __shfl_xor(gB, o);
        }
        if (l == 0) { redf[0][w] = swA; redf[1][w] = swB;
                      redg[0][w] = gA;  redg[1][w] = gB; }
    }
    __syncthreads();
    if (tid == 0) {
        float totA = (redf[0][0] + redf[0][1]) + (redf[0][2] + redf[0][3]);
        float totB = (redf[1][0] + redf[1][1]) + (redf[1][2] + redf[1][3]);
        float gtA  = (redg[0][0] + redg[0][1]) + (redg[0][2] + redg[0][3]);
        float gtB  = (redg[1][0] + redg[1][1]) + (redg[1][2] + redg[1][3]);
        float partA = M0A + SA * 0.69314718055994531f + __logf(totA);
        float partB = M0B + SB * 0.69314718055994531f + __logf(totB);
        atomicAdd(out, (partA - gtA) + (partB - gtB));
    }
}

extern "C" void kernel_launch(void* const* d_in, const int* in_sizes, int n_in,
                              void* d_out, int out_size, void* d_ws, size_t ws_size,
                              hipStream_t stream) {
    const float*         emissions = (const float*)d_in[0];
    const int*           tags      = (const int*)d_in[1];
    const unsigned char* mask      = (const unsigned char*)d_in[2];
    const float*         trans     = (const float*)d_in[3];
    float*               out       = (float*)d_out;

    zero_out_kernel<<<1, 1, 0, stream>>>(out);
    crf_fwd_kernel<<<128, 256, 0, stream>>>(emissions, tags, mask, trans, out);
}

// Round 7
// 244.369 us; speedup vs baseline: 1.4247x; 1.4247x over previous
//
#include <hip/hip_runtime.h>

#define NT 128
#define SS 512
#define PW 132                         // padded per-wave column stride (floats)

typedef float f32x2 __attribute__((ext_vector_type(2)));

__device__ __forceinline__ float rdlane(float v, int lane) {
    return __int_as_float(__builtin_amdgcn_readlane(__float_as_int(v), lane));
}
__device__ __forceinline__ int fexp_of(float x) {
    return (int)((__float_as_uint(x) >> 23) & 0xFFu) - 127;
}
// barrier draining only LDS ops — global prefetches stay in flight
__device__ __forceinline__ void lds_barrier() {
    asm volatile("s_waitcnt lgkmcnt(0)\n\ts_barrier" ::: "memory");
}

__global__ void zero_out_kernel(float* out) { out[0] = 0.0f; }

__global__ __launch_bounds__(256, 1) void crf_fwd_kernel(
    const float* __restrict__ emissions,        // [B, S, NT] f32
    const int* __restrict__ tags,               // [B, S]
    const unsigned char* __restrict__ mask,     // [B, S]
    const float* __restrict__ trans,            // [NT, NT] f32
    float* __restrict__ out)                    // [1] f32
{
    const int b   = blockIdx.x;                 // one batch per block
    const int tid = threadIdx.x;                // 0..255
    const int l   = tid & 63;
    const int w   = tid >> 6;                   // wave 0..3: rows/states 32w..32w+31
    const int st  = (w << 5) + (l & 31);        // owned state (dup on lane pairs)

    __shared__ float pbuf[2][4 * PW];           // [parity][wave*PW + col]
    __shared__ int   kbuf[4];
    __shared__ float redf[4];
    __shared__ float redg[4];

    const float*         emB = emissions + (size_t)b * SS * NT;
    const int*           tgB = tags + b * SS;
    const unsigned char* mkB = mask + b * SS;

    // ---- gold score fully hoisted off the recursion ----
    float gold = 0.0f;
    for (int t = tid; t < SS; t += 256) {
        int tg   = tgB[t];
        float mk = mkB[t] ? 1.0f : 0.0f;
        float a  = emB[(size_t)t * NT + tg];
        if (t > 0) a += trans[tgB[t - 1] * NT + tg];
        gold += a * mk;
    }

    // ---- expT: own 32 rows, cols {l, l+64} packed -> 64 VGPRs ----
    // asm identity pins each value: a non-rematerializable def forces true
    // VGPR residency (VGPR_Count=56 rounds proved LLVM was re-loading trans
    // and re-running v_exp_f32 inside every one of the 511 steps).
    f32x2 eTr[32];
    #pragma unroll
    for (int r = 0; r < 32; r++) {
        const float* row = trans + (size_t)((w << 5) + r) * NT;
        f32x2 v; v.x = __expf(row[l]); v.y = __expf(row[l + 64]);
        eTr[r] = v;
    }
    #pragma unroll
    for (int r = 0; r < 32; r++) {
        asm volatile("" : "+v"(eTr[r]));        // pin: defeat rematerialization
    }

    // ---- init: true alpha_j = p̂ * 2^S * e^{M0} (S global) ----
    float a0 = emB[st];
    {
        float v = a0;                            // max within 32-lane halves
        #pragma unroll
        for (int o = 16; o > 0; o >>= 1) v = fmaxf(v, __shfl_xor(v, o));
        if (l == 0) redf[w] = v;
    }
    __syncthreads();
    const float M0 = fmaxf(fmaxf(redf[0], redf[1]), fmaxf(redf[2], redf[3]));

    float p = __expf(a0 - M0);                  // p̂ for state st (duplicated)
    float S = 0.0f;
    int K = 0, kv_own = 0;

    // ---- emission pipeline: loads 4 deep, exp 2 steps off-chain ----
    float ex_o = __expf(emB[(size_t)1 * NT + st]);   // exp(e_1)
    float ex_e = __expf(emB[(size_t)2 * NT + st]);   // exp(e_2)
    float pd_o = emB[(size_t)3 * NT + st];
    float pd_e = emB[(size_t)4 * NT + st];

    // matvec over own 32 rows + 4-way partial combine; 1 lgkm barrier
    auto matvec = [&](int q, bool kw) -> float {
        f32x2 A0 = {0.f,0.f}, A1 = {0.f,0.f}, A2 = {0.f,0.f}, A3 = {0.f,0.f};
        #pragma unroll
        for (int r = 0; r < 32; r += 4) {
            float q0 = rdlane(p, r + 0);
            float q1 = rdlane(p, r + 1);
            float q2 = rdlane(p, r + 2);
            float q3 = rdlane(p, r + 3);
            f32x2 b0 = {q0, q0}, b1 = {q1, q1}, b2 = {q2, q2}, b3 = {q3, q3};
            A0 = __builtin_elementwise_fma(b0, eTr[r + 0], A0);
            A1 = __builtin_elementwise_fma(b1, eTr[r + 1], A1);
            A2 = __builtin_elementwise_fma(b2, eTr[r + 2], A2);
            A3 = __builtin_elementwise_fma(b3, eTr[r + 3], A3);
        }
        f32x2 s2 = (A0 + A1) + (A2 + A3);       // {partial col l, partial col l+64}
        pbuf[q][w * PW + l]      = s2.x;
        pbuf[q][w * PW + l + 64] = s2.y;
        if (kw && l == 0) kbuf[w] = kv_own;     // rides the barrier
        lds_barrier();                          // lgkm-only: vmcnt untouched
        return (pbuf[q][0 * PW + st] + pbuf[q][1 * PW + st]) +
               (pbuf[q][2 * PW + st] + pbuf[q][3 * PW + st]);
    };
    auto rot = [&](int t, float& pd, float& ex) {
        float nr = pd;
        int tn = t + 4; if (tn > SS - 1) tn = SS - 1;
        pd = emB[(size_t)tn * NT + st];
        ex = __expf(nr);
    };

    // ---- forward recursion: groups of 4 steps; rescale at sub-step 0 ----
    #pragma unroll 1
    for (int t = 1; t < SS; t += 4) {
        {   // sub 0 (parity 1): apply K, propose next kv (swizzles 1x/group)
            float sn = matvec(1, false) * ex_o;
            p = ldexpf(sn, -K);
            S += (float)K;
            int kv = fexp_of(p);
            #pragma unroll
            for (int o = 16; o > 0; o >>= 1) kv = max(kv, __shfl_xor(kv, o));
            kv_own = kv;
            rot(t, pd_o, ex_o);
        }
        if (t + 1 < SS) {   // sub 1 (parity 0): K exchange piggyback
            float sn = matvec(0, true) * ex_e;
            int k0 = kbuf[0], k1 = kbuf[1], k2 = kbuf[2], k3 = kbuf[3];
            K = max(max(k0, k1), max(k2, k3));
            p = sn;
            rot(t + 1, pd_e, ex_e);
        }
        if (t + 2 < SS) { p = matvec(1, false) * ex_o; rot(t + 2, pd_o, ex_o); }
        if (t + 3 < SS) { p = matvec(0, false) * ex_e; rot(t + 3, pd_e, ex_e); }
    }

    // ---- epilogue: partition = M0 + S*ln2 + log Σ p̂ ; reduce gold ----
    {
        float sw = (l < 32) ? p : 0.0f;         // states duplicated on lane pairs
        float g  = gold;
        #pragma unroll
        for (int o = 32; o > 0; o >>= 1) {
            sw += __shfl_xor(sw, o);
            g  += __shfl_xor(g, o);
        }
        if (l == 0) { redf[w] = sw; redg[w] = g; }
    }
    __syncthreads();
    if (tid == 0) {
        float tot  = (redf[0] + redf[1]) + (redf[2] + redf[3]);
        float part = M0 + S * 0.69314718055994531f + __logf(tot);
        float gt   = (redg[0] + redg[1]) + (redg[2] + redg[3]);
        atomicAdd(out, part - gt);
    }
}

extern "C" void kernel_launch(void* const* d_in, const int* in_sizes, int n_in,
                              void* d_out, int out_size, void* d_ws, size_t ws_size,
                              hipStream_t stream) {
    const float*         emissions = (const float*)d_in[0];
    const int*           tags      = (const int*)d_in[1];
    const unsigned char* mask      = (const unsigned char*)d_in[2];
    const float*         trans     = (const float*)d_in[3];
    float*               out       = (float*)d_out;

    zero_out_kernel<<<1, 1, 0, stream>>>(out);
    crf_fwd_kernel<<<256, 256, 0, stream>>>(emissions, tags, mask, trans, out);
}

// Round 8
// 200.528 us; speedup vs baseline: 1.7362x; 1.2186x over previous
//
#include <hip/hip_runtime.h>

#define NT 128
#define SS 512
#define MID 256
#define PW 132                         // padded per-wave column stride (floats)

// workspace layout (floats)
#define WSF_P 0                        // [256][128] forward alpha-hat at t=255
#define WSF_M (256 * 128)              // [256] M0f
#define WSF_S (WSF_M + 256)            // [256] Sf
#define WSB_P (WSF_S + 256)            // [256][128] backward q-hat at t=255
#define WSB_S (WSB_P + 256 * 128)      // [256] Sb

typedef float f32x2 __attribute__((ext_vector_type(2)));

__device__ __forceinline__ float rdlane(float v, int lane) {
    return __int_as_float(__builtin_amdgcn_readlane(__float_as_int(v), lane));
}
__device__ __forceinline__ int fexp_of(float x) {
    return (int)((__float_as_uint(x) >> 23) & 0xFFu) - 127;
}
// barrier draining only LDS ops — global prefetches stay in flight
__device__ __forceinline__ void lds_barrier() {
    asm volatile("s_waitcnt lgkmcnt(0)\n\ts_barrier" ::: "memory");
}

__global__ void zero_out_kernel(float* out) { out[0] = 0.0f; }

// Forward-backward split: blocks 0..255 run alpha (t=1..255), blocks 256..511
// run the backward vector q_t = eT*(ex_{t+1} o q_{t+1}) (t=510..255). Halves
// the sequential depth; 2 blocks/CU in different barrier groups fill each
// other's barrier-drain bubbles. Combine kernel: partition_b = M0f +
// (Sf+Sb)ln2 + log(alpha_255 . q_255).
__global__ __launch_bounds__(256, 2) void crf_fb_kernel(
    const float* __restrict__ emissions,        // [B, S, NT] f32
    const int* __restrict__ tags,               // [B, S]
    const unsigned char* __restrict__ mask,     // [B, S]
    const float* __restrict__ trans,            // [NT, NT] f32
    float* __restrict__ out,                    // [1] f32
    float* __restrict__ ws)                     // workspace
{
    const bool fw  = (blockIdx.x < 256);
    const int b    = blockIdx.x & 255;
    const int tid  = threadIdx.x;               // 0..255
    const int l    = tid & 63;
    const int w    = tid >> 6;                  // wave 0..3: rows/states 32w..32w+31
    const int st   = (w << 5) + (l & 31);       // owned state (dup on lane halves)

    __shared__ float pbuf[2][4 * PW];           // [parity][wave*PW + col]
    __shared__ int   kbuf[4];
    __shared__ float redf[4];
    __shared__ float redg[4];

    const float*         emB = emissions + (size_t)b * SS * NT;
    const int*           tgB = tags + b * SS;
    const unsigned char* mkB = mask + b * SS;

    // ---- gold score (forward blocks only; fully off the recursion) ----
    float gold = 0.0f;
    if (fw) {
        for (int t = tid; t < SS; t += 256) {
            int tg   = tgB[t];
            float mk = mkB[t] ? 1.0f : 0.0f;
            float a  = emB[(size_t)t * NT + tg];
            if (t > 0) a += trans[tgB[t - 1] * NT + tg];
            gold += a * mk;
        }
    }

    // ---- expT: forward = row-block slice; backward = transposed slice ----
    f32x2 eTr[32];
    if (fw) {
        #pragma unroll
        for (int r = 0; r < 32; r++) {
            const float* row = trans + (size_t)((w << 5) + r) * NT;
            f32x2 v; v.x = __expf(row[l]); v.y = __expf(row[l + 64]);
            eTr[r] = v;
        }
    } else {
        #pragma unroll
        for (int r = 0; r < 32; r++) {          // eTr[r] = exp(T[{l,l+64}][32w+r])
            f32x2 v;
            v.x = __expf(trans[(size_t)l * NT + (w << 5) + r]);
            v.y = __expf(trans[(size_t)(l + 64) * NT + (w << 5) + r]);
            eTr[r] = v;
        }
    }

    // ---- init state + emission pipeline (4 deep, exp 2 steps off-chain) ----
    float p, M0 = 0.0f, S = 0.0f;
    int K = 0, kv_own = 0;
    float ex_o, ex_e, pd_o, pd_e;
    if (fw) {
        float a0 = emB[st];
        float v = a0;
        #pragma unroll
        for (int o = 16; o > 0; o >>= 1) v = fmaxf(v, __shfl_xor(v, o));
        if (l == 0) redf[w] = v;
        __syncthreads();
        M0 = fmaxf(fmaxf(redf[0], redf[1]), fmaxf(redf[2], redf[3]));
        p  = __expf(a0 - M0);
        ex_o = __expf(emB[(size_t)1 * NT + st]);
        ex_e = __expf(emB[(size_t)2 * NT + st]);
        pd_o = emB[(size_t)3 * NT + st];
        pd_e = emB[(size_t)4 * NT + st];
    } else {
        p = 1.0f;                               // q_511 = 1
        ex_o = __expf(emB[(size_t)511 * NT + st]);
        ex_e = __expf(emB[(size_t)510 * NT + st]);
        pd_o = emB[(size_t)509 * NT + st];
        pd_e = emB[(size_t)508 * NT + st];
    }

    // matvec over own 32 rows of the slice + 4-way combine; 1 lgkm barrier.
    // src is the broadcast vector (fwd: alpha; bwd: ex o q premultiplied).
    auto mv = [&](int q, bool kw, float src) -> float {
        f32x2 A0 = {0.f,0.f}, A1 = {0.f,0.f}, A2 = {0.f,0.f}, A3 = {0.f,0.f};
        #pragma unroll
        for (int r = 0; r < 32; r += 4) {
            float q0 = rdlane(src, r + 0);
            float q1 = rdlane(src, r + 1);
            float q2 = rdlane(src, r + 2);
            float q3 = rdlane(src, r + 3);
            f32x2 b0 = {q0, q0}, b1 = {q1, q1}, b2 = {q2, q2}, b3 = {q3, q3};
            A0 = __builtin_elementwise_fma(b0, eTr[r + 0], A0);
            A1 = __builtin_elementwise_fma(b1, eTr[r + 1], A1);
            A2 = __builtin_elementwise_fma(b2, eTr[r + 2], A2);
            A3 = __builtin_elementwise_fma(b3, eTr[r + 3], A3);
        }
        f32x2 s2 = (A0 + A1) + (A2 + A3);       // {partial col l, partial col l+64}
        pbuf[q][w * PW + l]      = s2.x;
        pbuf[q][w * PW + l + 64] = s2.y;
        if (kw && l == 0) kbuf[w] = kv_own;     // rides the barrier
        lds_barrier();                          // lgkm-only: vmcnt untouched
        return (pbuf[q][0 * PW + st] + pbuf[q][1 * PW + st]) +
               (pbuf[q][2 * PW + st] + pbuf[q][3 * PW + st]);
    };
    auto rotF = [&](int t, float& pd, float& ex) {
        float nr = pd;
        int tn = t + 4; if (tn > SS - 1) tn = SS - 1;
        pd = emB[(size_t)tn * NT + st];
        ex = __expf(nr);
    };
    auto rotB = [&](int t, float& pd, float& ex) {
        float nr = pd;
        int tn = t - 3; if (tn < 0) tn = 0;
        pd = emB[(size_t)tn * NT + st];
        ex = __expf(nr);
    };

    // ---- recursion: groups of 4 steps; rescale at sub-step 0 ----
    if (fw) {
        #pragma unroll 1
        for (int t = 1; t < MID; t += 4) {
            {   // sub 0 (parity 1): apply K, propose next kv
                float sn = mv(1, false, p) * ex_o;
                p = ldexpf(sn, -K);
                S += (float)K;
                int kv = fexp_of(p);
                #pragma unroll
                for (int o = 16; o > 0; o >>= 1) kv = max(kv, __shfl_xor(kv, o));
                kv_own = kv;
                rotF(t, pd_o, ex_o);
            }
            if (t + 1 < MID) {   // sub 1 (parity 0): K exchange piggyback
                float sn = mv(0, true, p) * ex_e;
                K = max(max(kbuf[0], kbuf[1]), max(kbuf[2], kbuf[3]));
                p = sn;
                rotF(t + 1, pd_e, ex_e);
            }
            if (t + 2 < MID) { p = mv(1, false, p) * ex_o; rotF(t + 2, pd_o, ex_o); }
            if (t + 3 < MID) { p = mv(0, false, p) * ex_e; rotF(t + 3, pd_e, ex_e); }
        }
    } else {
        #pragma unroll 1
        for (int t = 510; t >= 258; t -= 4) {   // 64 full groups: q_510 .. q_255
            {   // sub 0 (parity 1)
                float sn = mv(1, false, p * ex_o);
                p = ldexpf(sn, -K);
                S += (float)K;
                int kv = fexp_of(p);
                #pragma unroll
                for (int o = 16; o > 0; o >>= 1) kv = max(kv, __shfl_xor(kv, o));
                kv_own = kv;
                rotB(t, pd_o, ex_o);
            }
            {   // sub 1 (parity 0)
                float sn = mv(0, true, p * ex_e);
                K = max(max(kbuf[0], kbuf[1]), max(kbuf[2], kbuf[3]));
                p = sn;
                rotB(t - 1, pd_e, ex_e);
            }
            { p = mv(1, false, p * ex_o); rotB(t - 2, pd_o, ex_o); }
            { p = mv(0, false, p * ex_e); rotB(t - 3, pd_e, ex_e); }
        }
    }

    // ---- epilogue: publish vectors + scales; forward also reduces gold ----
    if (l < 32) {
        ws[(fw ? WSF_P : WSB_P) + b * NT + st] = p;
    }
    if (fw) {
        float g = gold;
        #pragma unroll
        for (int o = 32; o > 0; o >>= 1) g += __shfl_xor(g, o);
        if (l == 0) redg[w] = g;
        __syncthreads();
        if (tid == 0) {
            ws[WSF_M + b] = M0;
            ws[WSF_S + b] = S;
            float gt = (redg[0] + redg[1]) + (redg[2] + redg[3]);
            atomicAdd(out, -gt);
        }
    } else {
        if (tid == 0) ws[WSB_S + b] = S;
    }
}

// partition_b = M0f + (Sf+Sb)*ln2 + log( sum_i alpha_hat[i] * q_hat[i] )
__global__ __launch_bounds__(64, 1) void crf_combine_kernel(
    const float* __restrict__ ws, float* __restrict__ out)
{
    const int b = blockIdx.x;
    const int l = threadIdx.x;                  // 0..63
    const float* pf = ws + WSF_P + b * NT;
    const float* pb = ws + WSB_P + b * NT;
    float d = pf[l] * pb[l] + pf[l + 64] * pb[l + 64];
    #pragma unroll
    for (int o = 32; o > 0; o >>= 1) d += __shfl_xor(d, o);
    if (l == 0) {
        float part = ws[WSF_M + b] +
                     (ws[WSF_S + b] + ws[WSB_S + b]) * 0.69314718055994531f +
                     __logf(d);
        atomicAdd(out, part);
    }
}

extern "C" void kernel_launch(void* const* d_in, const int* in_sizes, int n_in,
                              void* d_out, int out_size, void* d_ws, size_t ws_size,
                              hipStream_t stream) {
    const float*         emissions = (const float*)d_in[0];
    const int*           tags      = (const int*)d_in[1];
    const unsigned char* mask      = (const unsigned char*)d_in[2];
    const float*         trans     = (const float*)d_in[3];
    float*               out       = (float*)d_out;
    float*               ws        = (float*)d_ws;

    zero_out_kernel<<<1, 1, 0, stream>>>(out);
    crf_fb_kernel<<<512, 256, 0, stream>>>(emissions, tags, mask, trans, out, ws);
    crf_combine_kernel<<<256, 64, 0, stream>>>(ws, out);
}